// Round 1
// baseline (364.248 us; speedup 1.0000x reference)
//
#include <hip/hip_runtime.h>
#include <hip/hip_cooperative_groups.h>
#include <cmath>

#define NN 64
#define CC 256
#define TT 64
#define VV 25
#define OO 512     // 2*out_planes
#define GG 8
#define NV (NN*VV)   // 1600 elements per channel for qkv/so BN
#define STK 625      // V*V

namespace cg = cooperative_groups;

// ---------------- kernel 1: y[n,c,v] = mean_t x[n,c,t,v]  (+ zero stat accums) ----------------
__global__ __launch_bounds__(256) void k_mean(const float* __restrict__ x,
                                              float* __restrict__ y,
                                              float* __restrict__ accz) {
    __shared__ float tile[TT * VV];   // 1600 floats
    int b = blockIdx.x;               // n*CC + c
    if (b == 0) {
        // zero qacc(1024) | sacc(48) | oacc(1024) = 2096 floats (contiguous)
        for (int i = threadIdx.x; i < 2096; i += 256) accz[i] = 0.f;
    }
    const float4* x4 = (const float4*)(x + (size_t)b * (TT * VV));
    float4* t4 = (float4*)tile;
    for (int i = threadIdx.x; i < (TT * VV) / 4; i += 256) t4[i] = x4[i];
    __syncthreads();
    if (threadIdx.x < VV) {
        float s = 0.f;
        #pragma unroll
        for (int t = 0; t < TT; ++t) s += tile[t * VV + threadIdx.x];
        y[(size_t)b * VV + threadIdx.x] = s * (1.0f / TT);
    }
}

// ---------------- fused middle: gemm -> BN(qkv) -> scores -> BN(sim) -> softmax -> sv/sve ----------------
// grid = NN*GG = 512 blocks (2 per CU, co-resident via cooperative launch), 256 threads.
__global__ __launch_bounds__(256, 2) void k_mid(const float* __restrict__ y,
                                                const float* __restrict__ w,
                                                const float* __restrict__ rel,
                                                const float* __restrict__ gq,
                                                const float* __restrict__ bq,
                                                const float* __restrict__ gs,
                                                const float* __restrict__ bs,
                                                float* __restrict__ qacc,
                                                float* __restrict__ sacc,
                                                float* __restrict__ oacc,
                                                float* __restrict__ so) {
    cg::grid_group grid = cg::this_grid();

    __shared__ __align__(16) float ys[CC * (VV + 1)];   // 6656 f: y staging (P1), sv/sve staging (P3)
    __shared__ float qs[64 * (VV + 1)];                 // 1664 f: qkv for this (n,g), LDS-resident
    __shared__ float S3[3 * STK];                       // 1875 f: raw qk/qr/kr scores
    __shared__ float P[STK];                            // 625 f: BN-summed scores -> probabilities
    __shared__ float rs[32 * 49];                       // 1568 f: relative embedding half
    __shared__ float csc[64], csh[64];                  // qkv BN scale/shift for local channels
    __shared__ float simp[6];                           // sim BN scale/shift (3 channels)
    __shared__ float sred[24];                          // 4 waves x 6 partials

    const int tid = threadIdx.x;
    const int nb = blockIdx.x >> 3, gb = blockIdx.x & 7;

    // ===== P1: qkv gemm (64 channels x 25 v) into qs, + channel stats atomics =====
    {
        const float* yp = y + (size_t)nb * (CC * VV);
        for (int i = tid; i < CC * VV; i += 256) {
            int c = i / VV, v = i - c * VV;
            ys[c * (VV + 1) + v] = yp[i];
        }
        __syncthreads();
        if (tid < 200) {                       // 8 o-slots * 25 v
            int v = tid % VV, o0 = tid / VV;
            const float* wp = w + (size_t)(gb * 64 + o0) * CC;
            float acc[8] = {0, 0, 0, 0, 0, 0, 0, 0};
            for (int c = 0; c < CC; c += 4) {
                float y0 = ys[c * (VV + 1) + v],       y1 = ys[(c + 1) * (VV + 1) + v];
                float y2 = ys[(c + 2) * (VV + 1) + v], y3 = ys[(c + 3) * (VV + 1) + v];
                #pragma unroll
                for (int u = 0; u < 8; ++u) {
                    const float4 w4 = *(const float4*)(wp + (size_t)u * 8 * CC + c);
                    acc[u] += y0 * w4.x + y1 * w4.y + y2 * w4.z + y3 * w4.w;
                }
            }
            #pragma unroll
            for (int u = 0; u < 8; ++u) qs[(o0 + u * 8) * (VV + 1) + v] = acc[u];
        }
        __syncthreads();
        if (tid < 64) {
            float s = 0.f, s2 = 0.f;
            #pragma unroll
            for (int v = 0; v < VV; ++v) {
                float val = qs[tid * (VV + 1) + v];
                s += val; s2 += val * val;
            }
            atomicAdd(&qacc[gb * 64 + tid], s);
            atomicAdd(&qacc[512 + gb * 64 + tid], s2);
        }
    }
    grid.sync();

    // ===== P2: qkv BN inline, scores qk/qr/kr into S3, sim stats atomics =====
    {
        if (tid < 64) {
            int ch = gb * 64 + tid;
            float m = qacc[ch] * (1.0f / NV);
            float var = qacc[512 + ch] * (1.0f / NV) - m * m;
            float sc = gq[ch] * rsqrtf(var + 1e-5f);
            csc[tid] = sc;
            csh[tid] = bq[ch] - m * sc;
        }
        __syncthreads();
        for (int i = tid; i < 64 * VV; i += 256) {
            int c = i / VV, v = i - c * VV;
            qs[c * (VV + 1) + v] = qs[c * (VV + 1) + v] * csc[c] + csh[c];
        }
        for (int i = tid; i < 32 * 49; i += 256) rs[i] = rel[i];
        __syncthreads();
        float ls0 = 0.f, ls1 = 0.f, ls2 = 0.f, ls3 = 0.f, ls4 = 0.f, ls5 = 0.f;
        for (int ij = tid; ij < STK; ij += 256) {
            int i = ij / VV, j = ij - (ij / VV) * VV;
            float aqk = 0.f, aqr = 0.f, akr = 0.f;
            #pragma unroll
            for (int c = 0; c < 16; ++c) {
                float qv = qs[c * (VV + 1) + i], kv = qs[(16 + c) * (VV + 1) + j];
                aqk += qv * kv;
                aqr += qv * rs[c * 49 + i - j + 24];
                akr += kv * rs[(16 + c) * 49 + j - i + 24];
            }
            S3[ij] = aqk; S3[STK + ij] = aqr; S3[2 * STK + ij] = akr;
            ls0 += aqk; ls1 += aqk * aqk;
            ls2 += aqr; ls3 += aqr * aqr;
            ls4 += akr; ls5 += akr * akr;
        }
        #pragma unroll
        for (int off = 32; off > 0; off >>= 1) {
            ls0 += __shfl_down(ls0, off); ls1 += __shfl_down(ls1, off);
            ls2 += __shfl_down(ls2, off); ls3 += __shfl_down(ls3, off);
            ls4 += __shfl_down(ls4, off); ls5 += __shfl_down(ls5, off);
        }
        int lane = tid & 63, wid = tid >> 6;
        if (lane == 0) {
            sred[wid * 6 + 0] = ls0; sred[wid * 6 + 1] = ls1;
            sred[wid * 6 + 2] = ls2; sred[wid * 6 + 3] = ls3;
            sred[wid * 6 + 4] = ls4; sred[wid * 6 + 5] = ls5;
        }
        __syncthreads();
        if (tid < 6) {
            float t2 = sred[tid] + sred[6 + tid] + sred[12 + tid] + sred[18 + tid];
            int ch = (tid >> 1) * 8 + gb;          // 0:qk(g) 1:qr(8+g) 2:kr(16+g)
            atomicAdd(&sacc[(tid & 1) * 24 + ch], t2);
        }
    }
    grid.sync();

    // ===== P3: sim BN+sum, softmax, sv/sve, write so, out stats atomics =====
    {
        if (tid < 3) {
            int ch = tid * 8 + gb;
            float m = sacc[ch] * (1.0f / 40000.0f);
            float var = sacc[24 + ch] * (1.0f / 40000.0f) - m * m;
            float sc = gs[ch] * rsqrtf(var + 1e-5f);
            simp[tid * 2] = sc;
            simp[tid * 2 + 1] = bs[ch] - m * sc;
        }
        __syncthreads();
        for (int ij = tid; ij < STK; ij += 256)
            P[ij] = S3[ij] * simp[0] + simp[1]
                  + S3[STK + ij] * simp[2] + simp[3]
                  + S3[2 * STK + ij] * simp[4] + simp[5];
        for (int i = tid; i < 32 * 49; i += 256) rs[i] = rel[32 * 49 + i];
        __syncthreads();
        if (tid < VV) {
            const int i = tid;
            float mx = -1e30f;
            #pragma unroll
            for (int j = 0; j < VV; ++j) mx = fmaxf(mx, P[i * VV + j]);
            float e[VV]; float sum = 0.f;
            #pragma unroll
            for (int j = 0; j < VV; ++j) { e[j] = expf(P[i * VV + j] - mx); sum += e[j]; }
            float inv = 1.0f / sum;
            #pragma unroll
            for (int j = 0; j < VV; ++j) P[i * VV + j] = e[j] * inv;
        }
        __syncthreads();
        float* svs  = ys;          // reuse ys staging region (free since P1)
        float* sves = ys + 800;
        for (int idx = tid; idx < 800; idx += 256) {
            int c = idx / VV, i = idx - (idx / VV) * VV;
            float sv = 0.f, sve = 0.f;
            #pragma unroll
            for (int j = 0; j < VV; ++j) {
                float p = P[i * VV + j];
                sv  += p * qs[(32 + c) * (VV + 1) + j];
                sve += p * rs[c * 49 + i - j + 24];
            }
            svs[idx] = sv; sves[idx] = sve;
        }
        __syncthreads();
        if (tid < 64) {
            int c = tid >> 1;
            const float* src = (tid & 1) ? (sves + c * VV) : (svs + c * VV);
            float s = 0.f, s2 = 0.f;
            #pragma unroll
            for (int i = 0; i < VV; ++i) { float val = src[i]; s += val; s2 += val * val; }
            atomicAdd(&oacc[gb * 64 + tid], s);          // channel = g*64 + 2c + (tid&1)
            atomicAdd(&oacc[512 + gb * 64 + tid], s2);
        }
        float* sop = so + ((size_t)nb * OO + gb * 64) * VV;   // 1600 contiguous floats
        for (int idx = tid; idx < 1600; idx += 256) {
            int oc = idx / VV, i = idx - (idx / VV) * VV;
            int c = oc >> 1;
            sop[idx] = (oc & 1) ? sves[c * VV + i] : svs[c * VV + i];
        }
    }
}

// ---------------- kernel 3: out = x * (1 + sigmoid(bn(so[2p]) + bn(so[2p+1]))) ----------------
__global__ __launch_bounds__(256) void k_final(const float* __restrict__ x,
                                               const float* __restrict__ so,
                                               const float* __restrict__ oacc,
                                               const float* __restrict__ go,
                                               const float* __restrict__ bo,
                                               float* __restrict__ out) {
    int b = blockIdx.x;            // n*CC + p
    int n = b >> 8, p = b & 255;
    __shared__ float orow[VV];
    if (threadIdx.x < VV) {
        int o0 = 2 * p, o1 = 2 * p + 1;
        float m0 = oacc[o0] * (1.0f / NV);
        float var0 = oacc[512 + o0] * (1.0f / NV) - m0 * m0;
        float sc0 = go[o0] * rsqrtf(var0 + 1e-5f), sh0 = bo[o0] - m0 * sc0;
        float m1 = oacc[o1] * (1.0f / NV);
        float var1 = oacc[512 + o1] * (1.0f / NV) - m1 * m1;
        float sc1 = go[o1] * rsqrtf(var1 + 1e-5f), sh1 = bo[o1] - m1 * sc1;
        int v = threadIdx.x;
        float a  = so[((size_t)n * OO + o0) * VV + v] * sc0 + sh0;
        float c2 = so[((size_t)n * OO + o1) * VV + v] * sc1 + sh1;
        float z = a + c2;
        orow[v] = 1.0f + 1.0f / (1.0f + expf(-z));
    }
    __syncthreads();
    const float4* x4 = (const float4*)(x + (size_t)b * (TT * VV));
    float4* y4 = (float4*)(out + (size_t)b * (TT * VV));
    for (int wv = threadIdx.x; wv < (TT * VV) / 4; wv += 256) {
        float4 xv = x4[wv];
        int e = 4 * wv;
        int v0 = e % VV;
        float4 r;
        int v;
        v = v0;                      r.x = xv.x * orow[v];
        v = v0 + 1; if (v >= VV) v -= VV; r.y = xv.y * orow[v];
        v = v0 + 2; if (v >= VV) v -= VV; r.z = xv.z * orow[v];
        v = v0 + 3; if (v >= VV) v -= VV; r.w = xv.w * orow[v];
        y4[wv] = r;
    }
}

extern "C" void kernel_launch(void* const* d_in, const int* in_sizes, int n_in,
                              void* d_out, int out_size, void* d_ws, size_t ws_size,
                              hipStream_t stream) {
    (void)in_sizes; (void)n_in; (void)out_size; (void)ws_size;
    const float* x        = (const float*)d_in[0];
    const float* w_qkv    = (const float*)d_in[1];
    const float* relative = (const float*)d_in[2];
    const float* bn_qkv_g = (const float*)d_in[3];
    const float* bn_qkv_b = (const float*)d_in[4];
    const float* bn_sim_g = (const float*)d_in[5];
    const float* bn_sim_b = (const float*)d_in[6];
    const float* bn_out_g = (const float*)d_in[7];
    const float* bn_out_b = (const float*)d_in[8];
    float* out = (float*)d_out;

    float* ws = (float*)d_ws;
    float* w_y  = ws;                   // NN*CC*VV = 409600
    float* w_so = ws + 409600;          // NN*OO*VV = 819200
    float* qacc = ws + 1228800;         // 1024 (sum|sumsq per 512 ch)
    float* sacc = qacc + 1024;          // 48   (24 sums | 24 sumsq)
    float* oacc = sacc + 48;            // 1024

    k_mean<<<NN * CC, 256, 0, stream>>>(x, w_y, qacc);

    void* args[] = {(void*)&w_y, (void*)&w_qkv, (void*)&relative,
                    (void*)&bn_qkv_g, (void*)&bn_qkv_b,
                    (void*)&bn_sim_g, (void*)&bn_sim_b,
                    (void*)&qacc, (void*)&sacc, (void*)&oacc, (void*)&w_so};
    hipLaunchCooperativeKernel(k_mid, dim3(NN * GG), dim3(256), args, 0, stream);

    k_final<<<NN * CC, 256, 0, stream>>>(x, w_so, oacc, bn_out_g, bn_out_b, out);
}

// Round 2
// 277.537 us; speedup vs baseline: 1.3124x; 1.3124x over previous
//
#include <hip/hip_runtime.h>
#include <cmath>

#define NN 64
#define CC 256
#define TT 64
#define VV 25
#define OO 512     // 2*out_planes
#define GG 8
#define NV (NN*VV)   // 1600 elements per channel for qkv/so BN
#define STK 625      // V*V

// ---------------- kernel 1: y[n,c,v] = mean_t x[n,c,t,v]  (+ zero stat accums) ----------------
__global__ __launch_bounds__(256) void k_mean(const float* __restrict__ x,
                                              float* __restrict__ y,
                                              float* __restrict__ accz) {
    __shared__ float tile[TT * VV];   // 1600 floats
    int b = blockIdx.x;               // n*CC + c
    if (b == 0) {
        // zero qacc(1024) | sacc(48) | oacc(1024) = 2096 floats (contiguous)
        for (int i = threadIdx.x; i < 2096; i += 256) accz[i] = 0.f;
    }
    const float4* x4 = (const float4*)(x + (size_t)b * (TT * VV));
    float4* t4 = (float4*)tile;
    for (int i = threadIdx.x; i < (TT * VV) / 4; i += 256) t4[i] = x4[i];
    __syncthreads();
    if (threadIdx.x < VV) {
        float s = 0.f;
        #pragma unroll
        for (int t = 0; t < TT; ++t) s += tile[t * VV + threadIdx.x];
        y[(size_t)b * VV + threadIdx.x] = s * (1.0f / TT);
    }
}

// ---------------- kernel 2: qkv gemm + channel stats atomics ----------------
// grid = NN*8; block handles one n and a 64-wide o-chunk.
__global__ __launch_bounds__(256) void k_qkv(const float* __restrict__ y,
                                             const float* __restrict__ w,
                                             float* __restrict__ qkv,
                                             float* __restrict__ qacc) {
    __shared__ float ys[CC][VV + 1];  // stride 26 -> conflict-free scalar reads
    __shared__ float qs[64][VV + 1];
    int n = blockIdx.x >> 3, oc = blockIdx.x & 7;
    const float* yp = y + (size_t)n * CC * VV;
    for (int i = threadIdx.x; i < CC * VV; i += 256) ys[i / VV][i % VV] = yp[i];
    __syncthreads();
    int t = threadIdx.x;
    if (t < 200) {                    // 200 = 8 o-slots * 25 v
        int v = t % VV, o0 = t / VV;  // o0 in 0..7
        const float* wp = w + (size_t)(oc * 64 + o0) * CC;
        float acc[8] = {0, 0, 0, 0, 0, 0, 0, 0};
        for (int c = 0; c < CC; c += 4) {
            float y0 = ys[c][v], y1 = ys[c + 1][v], y2 = ys[c + 2][v], y3 = ys[c + 3][v];
            #pragma unroll
            for (int u = 0; u < 8; ++u) {
                const float4 w4 = *(const float4*)(wp + (size_t)u * 8 * CC + c);
                acc[u] += y0 * w4.x + y1 * w4.y + y2 * w4.z + y3 * w4.w;
            }
        }
        #pragma unroll
        for (int u = 0; u < 8; ++u) qs[o0 + u * 8][v] = acc[u];
    }
    __syncthreads();
    // coalesced global write of the 64x25 tile
    float* qp = qkv + ((size_t)n * OO + oc * 64) * VV;
    for (int i = t; i < 64 * VV; i += 256) qp[i] = qs[i / VV][i % VV];
    // per-channel partial stats -> atomics
    if (t < 64) {
        float s = 0.f, s2 = 0.f;
        #pragma unroll
        for (int v = 0; v < VV; ++v) { float val = qs[t][v]; s += val; s2 += val * val; }
        atomicAdd(&qacc[oc * 64 + t], s);
        atomicAdd(&qacc[512 + oc * 64 + t], s2);
    }
}

// ---------------- kernel 3: inline qkv-BN -> qk/qr/kr scores + sim stats atomics ----------------
__global__ __launch_bounds__(256) void k_scores(const float* __restrict__ qkv,
                                                const float* __restrict__ rel,
                                                const float* __restrict__ qacc,
                                                const float* __restrict__ gq,
                                                const float* __restrict__ bq,
                                                float* __restrict__ stk,
                                                float* __restrict__ sacc) {
    int n = blockIdx.x >> 3, gb = blockIdx.x & 7;
    __shared__ float qs[32][VV + 1];
    __shared__ float rs[32 * 49];
    __shared__ float csc[32], csh[32];
    __shared__ float sred[24];
    int t = threadIdx.x;
    if (t < 32) {
        int ch = gb * 64 + t;
        float m = qacc[ch] * (1.0f / NV);
        float var = qacc[512 + ch] * (1.0f / NV) - m * m;
        float sc = gq[ch] * rsqrtf(var + 1e-5f);
        csc[t] = sc; csh[t] = bq[ch] - m * sc;
    }
    __syncthreads();
    for (int i = t; i < 32 * VV; i += 256) {
        int c = i / VV, v = i - c * VV;
        qs[c][v] = qkv[((size_t)n * OO + gb * 64 + c) * VV + v] * csc[c] + csh[c];
    }
    for (int i = t; i < 32 * 49; i += 256) rs[i] = rel[i];
    __syncthreads();
    float ls0 = 0.f, ls1 = 0.f, ls2 = 0.f, ls3 = 0.f, ls4 = 0.f, ls5 = 0.f;
    size_t base = (size_t)n * 24;
    for (int ij = t; ij < STK; ij += 256) {
        int i = ij / VV, j = ij - (ij / VV) * VV;
        float aqk = 0.f, aqr = 0.f, akr = 0.f;
        #pragma unroll
        for (int c = 0; c < 16; ++c) {
            float qv = qs[c][i], kv = qs[16 + c][j];
            aqk += qv * kv;
            aqr += qv * rs[c * 49 + i - j + 24];
            akr += kv * rs[(16 + c) * 49 + j - i + 24];
        }
        stk[(base + gb) * STK + ij]      = aqk;
        stk[(base + 8 + gb) * STK + ij]  = aqr;
        stk[(base + 16 + gb) * STK + ij] = akr;
        ls0 += aqk; ls1 += aqk * aqk;
        ls2 += aqr; ls3 += aqr * aqr;
        ls4 += akr; ls5 += akr * akr;
    }
    #pragma unroll
    for (int off = 32; off > 0; off >>= 1) {
        ls0 += __shfl_down(ls0, off); ls1 += __shfl_down(ls1, off);
        ls2 += __shfl_down(ls2, off); ls3 += __shfl_down(ls3, off);
        ls4 += __shfl_down(ls4, off); ls5 += __shfl_down(ls5, off);
    }
    int lane = t & 63, wid = t >> 6;
    if (lane == 0) {
        sred[wid * 6 + 0] = ls0; sred[wid * 6 + 1] = ls1;
        sred[wid * 6 + 2] = ls2; sred[wid * 6 + 3] = ls3;
        sred[wid * 6 + 4] = ls4; sred[wid * 6 + 5] = ls5;
    }
    __syncthreads();
    if (t < 6) {
        float t2 = sred[t] + sred[6 + t] + sred[12 + t] + sred[18 + t];
        int ch = (t >> 1) * 8 + gb;          // 0:qk(g) 1:qr(8+g) 2:kr(16+g)
        atomicAdd(&sacc[(t & 1) * 24 + ch], t2);
    }
}

// ---------------- kernel 4: sim-BN+sum -> softmax -> sv/sve + out stats atomics ----------------
__global__ __launch_bounds__(256) void k_attnout(const float* __restrict__ stk,
                                                 const float* __restrict__ qkv,
                                                 const float* __restrict__ rel,
                                                 const float* __restrict__ qacc,
                                                 const float* __restrict__ gq,
                                                 const float* __restrict__ bq,
                                                 const float* __restrict__ sacc,
                                                 const float* __restrict__ gs,
                                                 const float* __restrict__ bs,
                                                 float* __restrict__ so,
                                                 float* __restrict__ oacc) {
    int n = blockIdx.x >> 3, gb = blockIdx.x & 7;
    __shared__ float S[STK];
    __shared__ float vs[32][VV + 1];
    __shared__ float rs[32 * 49];
    __shared__ float svs[800], sves[800];
    __shared__ float csc[32], csh[32];
    __shared__ float simp[6];
    int t = threadIdx.x;
    if (t < 32) {
        int ch = gb * 64 + 32 + t;
        float m = qacc[ch] * (1.0f / NV);
        float var = qacc[512 + ch] * (1.0f / NV) - m * m;
        float sc = gq[ch] * rsqrtf(var + 1e-5f);
        csc[t] = sc; csh[t] = bq[ch] - m * sc;
    }
    if (t < 3) {
        int ch = t * 8 + gb;
        float m = sacc[ch] * (1.0f / 40000.0f);
        float var = sacc[24 + ch] * (1.0f / 40000.0f) - m * m;
        float sc = gs[ch] * rsqrtf(var + 1e-5f);
        simp[t * 2] = sc; simp[t * 2 + 1] = bs[ch] - m * sc;
    }
    __syncthreads();
    const size_t sb = (size_t)n * 24 * STK;
    for (int ij = t; ij < STK; ij += 256)
        S[ij] = stk[sb + (size_t)gb * STK + ij] * simp[0] + simp[1]
              + stk[sb + (size_t)(8 + gb) * STK + ij] * simp[2] + simp[3]
              + stk[sb + (size_t)(16 + gb) * STK + ij] * simp[4] + simp[5];
    for (int i = t; i < 32 * VV; i += 256) {
        int c = i / VV, v = i - (i / VV) * VV;
        vs[c][v] = qkv[((size_t)n * OO + gb * 64 + 32 + c) * VV + v] * csc[c] + csh[c];
    }
    for (int i = t; i < 32 * 49; i += 256) rs[i] = rel[32 * 49 + i];
    __syncthreads();
    if (t < VV) {
        const int i = t;
        float mx = -1e30f;
        #pragma unroll
        for (int j = 0; j < VV; ++j) mx = fmaxf(mx, S[i * VV + j]);
        float e[VV]; float sum = 0.f;
        #pragma unroll
        for (int j = 0; j < VV; ++j) { e[j] = expf(S[i * VV + j] - mx); sum += e[j]; }
        float inv = 1.0f / sum;
        #pragma unroll
        for (int j = 0; j < VV; ++j) S[i * VV + j] = e[j] * inv;
    }
    __syncthreads();
    for (int idx = t; idx < 800; idx += 256) {
        int c = idx / VV, i = idx - (idx / VV) * VV;
        float sv = 0.f, sve = 0.f;
        #pragma unroll
        for (int j = 0; j < VV; ++j) {
            float p = S[i * VV + j];
            sv  += p * vs[c][j];
            sve += p * rs[c * 49 + i - j + 24];
        }
        svs[idx] = sv; sves[idx] = sve;
    }
    __syncthreads();
    if (t < 64) {
        int c = t >> 1;
        const float* src = (t & 1) ? (sves + c * VV) : (svs + c * VV);
        float s = 0.f, s2 = 0.f;
        #pragma unroll
        for (int i = 0; i < VV; ++i) { float val = src[i]; s += val; s2 += val * val; }
        atomicAdd(&oacc[gb * 64 + t], s);          // channel = g*64 + 2c + (t&1)
        atomicAdd(&oacc[512 + gb * 64 + t], s2);
    }
    float* sop = so + ((size_t)n * OO + gb * 64) * VV;   // 1600 contiguous floats
    for (int idx = t; idx < 1600; idx += 256) {
        int oc = idx / VV, i = idx - (idx / VV) * VV;
        int c = oc >> 1;
        sop[idx] = (oc & 1) ? sves[c * VV + i] : svs[c * VV + i];
    }
}

// ---------------- kernel 5: out = x * (1 + sigmoid(bn(so[2p]) + bn(so[2p+1]))) ----------------
__global__ __launch_bounds__(256) void k_final(const float* __restrict__ x,
                                               const float* __restrict__ so,
                                               const float* __restrict__ oacc,
                                               const float* __restrict__ go,
                                               const float* __restrict__ bo,
                                               float* __restrict__ out) {
    int b = blockIdx.x;            // n*CC + p
    int n = b >> 8, p = b & 255;
    __shared__ float orow[VV];
    if (threadIdx.x < VV) {
        int o0 = 2 * p, o1 = 2 * p + 1;
        float m0 = oacc[o0] * (1.0f / NV);
        float var0 = oacc[512 + o0] * (1.0f / NV) - m0 * m0;
        float sc0 = go[o0] * rsqrtf(var0 + 1e-5f), sh0 = bo[o0] - m0 * sc0;
        float m1 = oacc[o1] * (1.0f / NV);
        float var1 = oacc[512 + o1] * (1.0f / NV) - m1 * m1;
        float sc1 = go[o1] * rsqrtf(var1 + 1e-5f), sh1 = bo[o1] - m1 * sc1;
        int v = threadIdx.x;
        float a  = so[((size_t)n * OO + o0) * VV + v] * sc0 + sh0;
        float c2 = so[((size_t)n * OO + o1) * VV + v] * sc1 + sh1;
        float z = a + c2;
        orow[v] = 1.0f + 1.0f / (1.0f + expf(-z));
    }
    __syncthreads();
    const float4* x4 = (const float4*)(x + (size_t)b * (TT * VV));
    float4* y4 = (float4*)(out + (size_t)b * (TT * VV));
    for (int wv = threadIdx.x; wv < (TT * VV) / 4; wv += 256) {
        float4 xv = x4[wv];
        int e = 4 * wv;
        int v0 = e % VV;
        float4 r;
        int v;
        v = v0;                      r.x = xv.x * orow[v];
        v = v0 + 1; if (v >= VV) v -= VV; r.y = xv.y * orow[v];
        v = v0 + 2; if (v >= VV) v -= VV; r.z = xv.z * orow[v];
        v = v0 + 3; if (v >= VV) v -= VV; r.w = xv.w * orow[v];
        y4[wv] = r;
    }
}

extern "C" void kernel_launch(void* const* d_in, const int* in_sizes, int n_in,
                              void* d_out, int out_size, void* d_ws, size_t ws_size,
                              hipStream_t stream) {
    (void)in_sizes; (void)n_in; (void)out_size; (void)ws_size;
    const float* x        = (const float*)d_in[0];
    const float* w_qkv    = (const float*)d_in[1];
    const float* relative = (const float*)d_in[2];
    const float* bn_qkv_g = (const float*)d_in[3];
    const float* bn_qkv_b = (const float*)d_in[4];
    const float* bn_sim_g = (const float*)d_in[5];
    const float* bn_sim_b = (const float*)d_in[6];
    const float* bn_out_g = (const float*)d_in[7];
    const float* bn_out_b = (const float*)d_in[8];
    float* out = (float*)d_out;

    float* ws = (float*)d_ws;
    float* w_y    = ws;                 // NN*CC*VV = 409600
    float* w_qkvp = ws + 409600;        // NN*OO*VV = 819200
    float* w_stk  = ws + 1228800;       // NN*24*STK = 960000
    float* w_so   = ws + 2188800;       // NN*OO*VV = 819200
    float* qacc   = ws + 3008000;       // 1024 (sum | sumsq per 512 ch)
    float* sacc   = qacc + 1024;        // 48   (24 sums | 24 sumsq)
    float* oacc   = sacc + 48;          // 1024

    k_mean<<<NN * CC, 256, 0, stream>>>(x, w_y, qacc);
    k_qkv<<<NN * 8, 256, 0, stream>>>(w_y, w_qkv, w_qkvp, qacc);
    k_scores<<<NN * GG, 256, 0, stream>>>(w_qkvp, relative, qacc, bn_qkv_g, bn_qkv_b, w_stk, sacc);
    k_attnout<<<NN * GG, 256, 0, stream>>>(w_stk, w_qkvp, relative, qacc, bn_qkv_g, bn_qkv_b,
                                           sacc, bn_sim_g, bn_sim_b, w_so, oacc);
    k_final<<<NN * CC, 256, 0, stream>>>(x, w_so, oacc, bn_out_g, bn_out_b, out);
}

// Round 3
// 276.995 us; speedup vs baseline: 1.3150x; 1.0020x over previous
//
#include <hip/hip_runtime.h>
#include <cmath>

#define NN 64
#define CC 256
#define TT 64
#define VV 25
#define OO 512     // 2*out_planes
#define GG 8
#define NV (NN*VV)   // 1600 elements per channel for qkv/so BN
#define STK 625      // V*V

typedef float f4 __attribute__((ext_vector_type(4)));

// ---------------- kernel 1: y[n,c,v] = mean_t x[n,c,t,v]  (+ zero stat accums) ----------------
__global__ __launch_bounds__(256) void k_mean(const float* __restrict__ x,
                                              float* __restrict__ y,
                                              float* __restrict__ accz) {
    __shared__ float tile[TT * VV];   // 1600 floats
    __shared__ float part[8][VV];
    int b = blockIdx.x;               // n*CC + c
    if (b == 0) {
        // zero qacc(1024) | sacc(48) | oacc(1024) = 2096 floats (contiguous)
        for (int i = threadIdx.x; i < 2096; i += 256) accz[i] = 0.f;
    }
    const float4* x4 = (const float4*)(x + (size_t)b * (TT * VV));
    float4* t4 = (float4*)tile;
    for (int i = threadIdx.x; i < (TT * VV) / 4; i += 256) t4[i] = x4[i];
    __syncthreads();
    int t = threadIdx.x;
    if (t < 200) {                    // 25 v * 8 t-chunks
        int v = t % VV, ch = t / VV;
        float s = 0.f;
        #pragma unroll
        for (int k = 0; k < 8; ++k) s += tile[(ch * 8 + k) * VV + v];
        part[ch][v] = s;
    }
    __syncthreads();
    if (t < VV) {
        float s = 0.f;
        #pragma unroll
        for (int k = 0; k < 8; ++k) s += part[k][t];
        y[(size_t)b * VV + t] = s * (1.0f / TT);
    }
}

// ---------------- kernel 2: qkv gemm + channel stats atomics ----------------
// grid = NN*8; block handles one n and a 64-wide o-chunk.
__global__ __launch_bounds__(256) void k_qkv(const float* __restrict__ y,
                                             const float* __restrict__ w,
                                             float* __restrict__ qkv,
                                             float* __restrict__ qacc) {
    __shared__ float ys[CC][VV + 1];  // stride 26 -> conflict-free scalar reads
    __shared__ float qs[64][VV + 1];
    int n = blockIdx.x >> 3, oc = blockIdx.x & 7;
    const float* yp = y + (size_t)n * CC * VV;
    for (int i = threadIdx.x; i < CC * VV; i += 256) ys[i / VV][i % VV] = yp[i];
    __syncthreads();
    int t = threadIdx.x;
    if (t < 200) {                    // 200 = 8 o-slots * 25 v
        int v = t % VV, o0 = t / VV;  // o0 in 0..7
        const float* wp = w + (size_t)(oc * 64 + o0) * CC;
        float acc[8] = {0, 0, 0, 0, 0, 0, 0, 0};
        for (int c = 0; c < CC; c += 8) {
            float y0 = ys[c][v],     y1 = ys[c + 1][v], y2 = ys[c + 2][v], y3 = ys[c + 3][v];
            float y4_ = ys[c + 4][v], y5 = ys[c + 5][v], y6 = ys[c + 6][v], y7 = ys[c + 7][v];
            #pragma unroll
            for (int u = 0; u < 8; ++u) {
                const float4 wa = *(const float4*)(wp + (size_t)u * 8 * CC + c);
                const float4 wb = *(const float4*)(wp + (size_t)u * 8 * CC + c + 4);
                acc[u] += y0 * wa.x + y1 * wa.y + y2 * wa.z + y3 * wa.w
                        + y4_ * wb.x + y5 * wb.y + y6 * wb.z + y7 * wb.w;
            }
        }
        #pragma unroll
        for (int u = 0; u < 8; ++u) qs[o0 + u * 8][v] = acc[u];
    }
    __syncthreads();
    // coalesced global write of the 64x25 tile
    float* qp = qkv + ((size_t)n * OO + oc * 64) * VV;
    for (int i = t; i < 64 * VV; i += 256) qp[i] = qs[i / VV][i % VV];
    // per-channel partial stats -> atomics
    if (t < 64) {
        float s = 0.f, s2 = 0.f;
        #pragma unroll
        for (int v = 0; v < VV; ++v) { float val = qs[t][v]; s += val; s2 += val * val; }
        atomicAdd(&qacc[oc * 64 + t], s);
        atomicAdd(&qacc[512 + oc * 64 + t], s2);
    }
}

// ---------------- kernel 3: inline qkv-BN -> qk/qr/kr scores + sim stats atomics ----------------
__global__ __launch_bounds__(256) void k_scores(const float* __restrict__ qkv,
                                                const float* __restrict__ rel,
                                                const float* __restrict__ qacc,
                                                const float* __restrict__ gq,
                                                const float* __restrict__ bq,
                                                float* __restrict__ stk,
                                                float* __restrict__ sacc) {
    int n = blockIdx.x >> 3, gb = blockIdx.x & 7;
    __shared__ float qs[32][VV + 1];
    __shared__ float rs[32 * 49];
    __shared__ float csc[32], csh[32];
    __shared__ float sred[24];
    int t = threadIdx.x;
    if (t < 32) {
        int ch = gb * 64 + t;
        float m = qacc[ch] * (1.0f / NV);
        float var = qacc[512 + ch] * (1.0f / NV) - m * m;
        float sc = gq[ch] * rsqrtf(var + 1e-5f);
        csc[t] = sc; csh[t] = bq[ch] - m * sc;
    }
    __syncthreads();
    for (int i = t; i < 32 * VV; i += 256) {
        int c = i / VV, v = i - c * VV;
        qs[c][v] = qkv[((size_t)n * OO + gb * 64 + c) * VV + v] * csc[c] + csh[c];
    }
    for (int i = t; i < 32 * 49; i += 256) rs[i] = rel[i];
    __syncthreads();
    float ls0 = 0.f, ls1 = 0.f, ls2 = 0.f, ls3 = 0.f, ls4 = 0.f, ls5 = 0.f;
    size_t base = (size_t)n * 24;
    for (int ij = t; ij < STK; ij += 256) {
        int i = ij / VV, j = ij - (ij / VV) * VV;
        float aqk = 0.f, aqr = 0.f, akr = 0.f;
        #pragma unroll
        for (int c = 0; c < 16; ++c) {
            float qv = qs[c][i], kv = qs[16 + c][j];
            aqk += qv * kv;
            aqr += qv * rs[c * 49 + i - j + 24];
            akr += kv * rs[(16 + c) * 49 + j - i + 24];
        }
        stk[(base + gb) * STK + ij]      = aqk;
        stk[(base + 8 + gb) * STK + ij]  = aqr;
        stk[(base + 16 + gb) * STK + ij] = akr;
        ls0 += aqk; ls1 += aqk * aqk;
        ls2 += aqr; ls3 += aqr * aqr;
        ls4 += akr; ls5 += akr * akr;
    }
    #pragma unroll
    for (int off = 32; off > 0; off >>= 1) {
        ls0 += __shfl_down(ls0, off); ls1 += __shfl_down(ls1, off);
        ls2 += __shfl_down(ls2, off); ls3 += __shfl_down(ls3, off);
        ls4 += __shfl_down(ls4, off); ls5 += __shfl_down(ls5, off);
    }
    int lane = t & 63, wid = t >> 6;
    if (lane == 0) {
        sred[wid * 6 + 0] = ls0; sred[wid * 6 + 1] = ls1;
        sred[wid * 6 + 2] = ls2; sred[wid * 6 + 3] = ls3;
        sred[wid * 6 + 4] = ls4; sred[wid * 6 + 5] = ls5;
    }
    __syncthreads();
    if (t < 6) {
        float t2 = sred[t] + sred[6 + t] + sred[12 + t] + sred[18 + t];
        int ch = (t >> 1) * 8 + gb;          // 0:qk(g) 1:qr(8+g) 2:kr(16+g)
        atomicAdd(&sacc[(t & 1) * 24 + ch], t2);
    }
}

// ---------------- kernel 4: sim-BN+sum -> softmax -> sv/sve + out stats atomics ----------------
__global__ __launch_bounds__(256) void k_attnout(const float* __restrict__ stk,
                                                 const float* __restrict__ qkv,
                                                 const float* __restrict__ rel,
                                                 const float* __restrict__ qacc,
                                                 const float* __restrict__ gq,
                                                 const float* __restrict__ bq,
                                                 const float* __restrict__ sacc,
                                                 const float* __restrict__ gs,
                                                 const float* __restrict__ bs,
                                                 float* __restrict__ so,
                                                 float* __restrict__ oacc) {
    int n = blockIdx.x >> 3, gb = blockIdx.x & 7;
    __shared__ float S[STK];
    __shared__ float vs[32][VV + 1];
    __shared__ float rs[32 * 49];
    __shared__ float svs[800], sves[800];
    __shared__ float csc[32], csh[32];
    __shared__ float simp[6];
    int t = threadIdx.x;
    if (t < 32) {
        int ch = gb * 64 + 32 + t;
        float m = qacc[ch] * (1.0f / NV);
        float var = qacc[512 + ch] * (1.0f / NV) - m * m;
        float sc = gq[ch] * rsqrtf(var + 1e-5f);
        csc[t] = sc; csh[t] = bq[ch] - m * sc;
    }
    if (t < 3) {
        int ch = t * 8 + gb;
        float m = sacc[ch] * (1.0f / 40000.0f);
        float var = sacc[24 + ch] * (1.0f / 40000.0f) - m * m;
        float sc = gs[ch] * rsqrtf(var + 1e-5f);
        simp[t * 2] = sc; simp[t * 2 + 1] = bs[ch] - m * sc;
    }
    __syncthreads();
    const size_t sb = (size_t)n * 24 * STK;
    for (int ij = t; ij < STK; ij += 256)
        S[ij] = stk[sb + (size_t)gb * STK + ij] * simp[0] + simp[1]
              + stk[sb + (size_t)(8 + gb) * STK + ij] * simp[2] + simp[3]
              + stk[sb + (size_t)(16 + gb) * STK + ij] * simp[4] + simp[5];
    for (int i = t; i < 32 * VV; i += 256) {
        int c = i / VV, v = i - (i / VV) * VV;
        vs[c][v] = qkv[((size_t)n * OO + gb * 64 + 32 + c) * VV + v] * csc[c] + csh[c];
    }
    for (int i = t; i < 32 * 49; i += 256) rs[i] = rel[32 * 49 + i];
    __syncthreads();
    // wave-parallel softmax: 25 rows x 8 lanes
    if (t < 200) {
        int i = t >> 3, l = t & 7;
        float mx = -1e30f;
        for (int j = l; j < VV; j += 8) mx = fmaxf(mx, S[i * VV + j]);
        #pragma unroll
        for (int off = 4; off > 0; off >>= 1) mx = fmaxf(mx, __shfl_xor(mx, off));
        float sum = 0.f;
        for (int j = l; j < VV; j += 8) {
            float e = expf(S[i * VV + j] - mx);
            S[i * VV + j] = e;
            sum += e;
        }
        #pragma unroll
        for (int off = 4; off > 0; off >>= 1) sum += __shfl_xor(sum, off);
        float inv = 1.0f / sum;
        for (int j = l; j < VV; j += 8) S[i * VV + j] *= inv;
    }
    __syncthreads();
    for (int idx = t; idx < 800; idx += 256) {
        int c = idx / VV, i = idx - (idx / VV) * VV;
        float sv = 0.f, sve = 0.f;
        #pragma unroll
        for (int j = 0; j < VV; ++j) {
            float p = S[i * VV + j];
            sv  += p * vs[c][j];
            sve += p * rs[c * 49 + i - j + 24];
        }
        svs[idx] = sv; sves[idx] = sve;
    }
    __syncthreads();
    if (t < 64) {
        int c = t >> 1;
        const float* src = (t & 1) ? (sves + c * VV) : (svs + c * VV);
        float s = 0.f, s2 = 0.f;
        #pragma unroll
        for (int i = 0; i < VV; ++i) { float val = src[i]; s += val; s2 += val * val; }
        atomicAdd(&oacc[gb * 64 + t], s);          // channel = g*64 + 2c + (t&1)
        atomicAdd(&oacc[512 + gb * 64 + t], s2);
    }
    float* sop = so + ((size_t)n * OO + gb * 64) * VV;   // 1600 contiguous floats
    for (int idx = t; idx < 1600; idx += 256) {
        int oc = idx / VV, i = idx - (idx / VV) * VV;
        int c = oc >> 1;
        sop[idx] = (oc & 1) ? sves[c * VV + i] : svs[c * VV + i];
    }
}

// ---------------- kernel 5: out = x * (1 + sigmoid(bn(so[2p]) + bn(so[2p+1]))) ----------------
// Reverse block order: start on the x-tail still resident in L3 from k_mean.
// Non-temporal x loads (read-once) and out stores (write-once) keep x in L3.
__global__ __launch_bounds__(256) void k_final(const float* __restrict__ x,
                                               const float* __restrict__ so,
                                               const float* __restrict__ oacc,
                                               const float* __restrict__ go,
                                               const float* __restrict__ bo,
                                               float* __restrict__ out) {
    int b = (NN * CC - 1) - blockIdx.x;    // n*CC + p, reversed
    int n = b >> 8, p = b & 255;
    __shared__ float orow[VV];
    if (threadIdx.x < VV) {
        int o0 = 2 * p, o1 = 2 * p + 1;
        float m0 = oacc[o0] * (1.0f / NV);
        float var0 = oacc[512 + o0] * (1.0f / NV) - m0 * m0;
        float sc0 = go[o0] * rsqrtf(var0 + 1e-5f), sh0 = bo[o0] - m0 * sc0;
        float m1 = oacc[o1] * (1.0f / NV);
        float var1 = oacc[512 + o1] * (1.0f / NV) - m1 * m1;
        float sc1 = go[o1] * rsqrtf(var1 + 1e-5f), sh1 = bo[o1] - m1 * sc1;
        int v = threadIdx.x;
        float a  = so[((size_t)n * OO + o0) * VV + v] * sc0 + sh0;
        float c2 = so[((size_t)n * OO + o1) * VV + v] * sc1 + sh1;
        float z = a + c2;
        orow[v] = 1.0f + 1.0f / (1.0f + expf(-z));
    }
    __syncthreads();
    const f4* x4 = (const f4*)(x + (size_t)b * (TT * VV));
    f4* y4 = (f4*)(out + (size_t)b * (TT * VV));
    for (int wv = threadIdx.x; wv < (TT * VV) / 4; wv += 256) {
        f4 xv = __builtin_nontemporal_load(&x4[wv]);
        int e = 4 * wv;
        int v0 = e % VV;
        f4 r;
        int v;
        v = v0;                      r.x = xv.x * orow[v];
        v = v0 + 1; if (v >= VV) v -= VV; r.y = xv.y * orow[v];
        v = v0 + 2; if (v >= VV) v -= VV; r.z = xv.z * orow[v];
        v = v0 + 3; if (v >= VV) v -= VV; r.w = xv.w * orow[v];
        __builtin_nontemporal_store(r, &y4[wv]);
    }
}

extern "C" void kernel_launch(void* const* d_in, const int* in_sizes, int n_in,
                              void* d_out, int out_size, void* d_ws, size_t ws_size,
                              hipStream_t stream) {
    (void)in_sizes; (void)n_in; (void)out_size; (void)ws_size;
    const float* x        = (const float*)d_in[0];
    const float* w_qkv    = (const float*)d_in[1];
    const float* relative = (const float*)d_in[2];
    const float* bn_qkv_g = (const float*)d_in[3];
    const float* bn_qkv_b = (const float*)d_in[4];
    const float* bn_sim_g = (const float*)d_in[5];
    const float* bn_sim_b = (const float*)d_in[6];
    const float* bn_out_g = (const float*)d_in[7];
    const float* bn_out_b = (const float*)d_in[8];
    float* out = (float*)d_out;

    float* ws = (float*)d_ws;
    float* w_y    = ws;                 // NN*CC*VV = 409600
    float* w_qkvp = ws + 409600;        // NN*OO*VV = 819200
    float* w_stk  = ws + 1228800;       // NN*24*STK = 960000
    float* w_so   = ws + 2188800;       // NN*OO*VV = 819200
    float* qacc   = ws + 3008000;       // 1024 (sum | sumsq per 512 ch)
    float* sacc   = qacc + 1024;        // 48   (24 sums | 24 sumsq)
    float* oacc   = sacc + 48;          // 1024

    k_mean<<<NN * CC, 256, 0, stream>>>(x, w_y, qacc);
    k_qkv<<<NN * 8, 256, 0, stream>>>(w_y, w_qkv, w_qkvp, qacc);
    k_scores<<<NN * GG, 256, 0, stream>>>(w_qkvp, relative, qacc, bn_qkv_g, bn_qkv_b, w_stk, sacc);
    k_attnout<<<NN * GG, 256, 0, stream>>>(w_stk, w_qkvp, relative, qacc, bn_qkv_g, bn_qkv_b,
                                           sacc, bn_sim_g, bn_sim_b, w_so, oacc);
    k_final<<<NN * CC, 256, 0, stream>>>(x, w_so, oacc, bn_out_g, bn_out_b, out);
}